// Round 5
// baseline (2143.611 us; speedup 1.0000x reference)
//
#include <hip/hip_runtime.h>
#include <hip/hip_fp16.h>

#define BB 2048
#define SS 512
#define FF 32
#define HH 128
#define TO 24

typedef unsigned int uint;
using half4 = __attribute__((ext_vector_type(4))) _Float16;
using half8 = __attribute__((ext_vector_type(8))) _Float16;
using f32x4 = __attribute__((ext_vector_type(4))) float;

// ---- workspace layout (bytes) ----
#define OFF_ENCOUT 0ull                                      // half[B][S][H]
#define OFF_HFIN  (OFF_ENCOUT + (size_t)BB*SS*HH*2)          // float[B][H]
#define OFF_ATTNF (OFF_HFIN + (size_t)BB*HH*4)               // half[81920]  logits B-frags
#define OFF_DECF  (OFF_ATTNF + (size_t)81920*2)              // half[98304]  GRU B-frags
#define OFF_OUT1T (OFF_DECF + (size_t)98304*2)               // half[128*32]
#define OFF_WF    (OFF_OUT1T + (size_t)4096*2)               // half[61440]  enc B-frags

// ================= prep: pack weights into MFMA fragment order (unchanged) =================
__global__ void prep_kernel(const float* attn_W, const float* dec_Wih, const float* dec_Whh,
                            const float* out1_W, const float* enc_Wih, const float* enc_Whh,
                            __half* attnF, __half* decF, __half* out1T, __half* Wf) {
  int i = blockIdx.x * 256 + threadIdx.x;
  if (i < 81920) {
    int e = i & 7, l = (i >> 3) & 63, kb = (i >> 9) % 5, st = (i / 2560) & 7, w = i / 20480;
    int k = kb*32 + ((l >> 4) << 3) + e;
    int s = w*128 + st*16 + (l & 15);
    attnF[i] = __float2half(attn_W[s*160 + k]);
    return;
  }
  i -= 81920;
  if (i < 98304) {
    int e = i & 7, l = (i >> 3) & 63, fi = (i >> 9) % 48, w = i / 24576;
    int lq = l >> 4, l15 = l & 15;
    float val;
    if (fi < 32) {            // r/z combined [ctx|h] K=256
      int g2 = fi >> 4, sub = (fi >> 3) & 1, kb = fi & 7;
      int k = kb*32 + lq*8 + e, j = w*32 + sub*16 + l15, jg = g2*128 + j;
      val = (k < 128) ? dec_Wih[jg*128 + k] : dec_Whh[jg*128 + (k - 128)];
    } else {                  // nh (Whh) then ni (Wih), K=128 each
      int f2 = fi - 32, cat = f2 >> 3, sub = (f2 >> 2) & 1, kb4 = f2 & 3;
      int k = kb4*32 + lq*8 + e, j = 256 + w*32 + sub*16 + l15;
      val = cat ? dec_Wih[j*128 + k] : dec_Whh[j*128 + k];
    }
    decF[i] = __float2half(val);
    return;
  }
  i -= 98304;
  if (i < 4096) {
    int k = i >> 5, f = i & 31;
    out1T[i] = __float2half(out1_W[f*128 + k]);
    return;
  }
  i -= 4096;
  if (i < 61440) {
    int e = i & 7, l = (i >> 3) & 63, q = i >> 9;
    int kb = q % 5, tt = (q / 5) % 6, w = q / 30;
    int g = tt >> 1, sub = tt & 1;
    int k = kb*32 + ((l >> 4) << 3) + e;
    int J = g*128 + w*32 + sub*16 + (l & 15);
    float v = (k < 128) ? enc_Whh[J*128 + k] : enc_Wih[J*32 + (k - 128)];
    Wf[i] = __float2half(v);
  }
}

// ================= encoder: MFMA, 4 batches/block, 512 blocks (2/CU) =================
#define HXS 168

__global__ void __launch_bounds__(256, 1) enc_kernel(
    const float* __restrict__ xb, const __half* __restrict__ Wf,
    const float* __restrict__ bih, const float* __restrict__ bhh,
    __half* __restrict__ enc_out, float* __restrict__ hfin) {
  __shared__ __align__(16) _Float16 hx[16][HXS];   // rows 0..3 live, 4..15 zero
  const int tid  = threadIdx.x;
  const int lane = tid & 63, wid = tid >> 6;
  const int l15  = lane & 15, lq = lane >> 4;
  const int b0   = blockIdx.x * 4;

  half8 Bf[6][5];
  { const half8* wfp = (const half8*)Wf;
    #pragma unroll
    for (int tt = 0; tt < 6; ++tt)
      #pragma unroll
      for (int kb = 0; kb < 5; ++kb)
        Bf[tt][kb] = wfp[((wid*6 + tt)*5 + kb)*64 + lane];
  }

  float br[2], bz[2], bnh[2], bni[2];
  #pragma unroll
  for (int sub = 0; sub < 2; ++sub) {
    int j = wid*32 + sub*16 + l15;
    br[sub]  = bih[j]       + bhh[j];
    bz[sub]  = bih[128 + j] + bhh[128 + j];
    bnh[sub] = bhh[256 + j];
    bni[sub] = bih[256 + j];
  }
  float hreg[2][4] = {{0.f,0.f,0.f,0.f},{0.f,0.f,0.f,0.f}};

  const int m2 = (tid >> 5) & 3, c2 = tid & 31;   // staging: 4 rows x 32 cols (tid<128)

  for (int i = tid; i < 16*HXS; i += 256) (&hx[0][0])[i] = (_Float16)0.f;
  __syncthreads();
  if (tid < 128) hx[m2][128 + c2] = (_Float16)xb[((size_t)(b0 + m2)*512 + 0)*32 + c2];
  __syncthreads();

  for (int t = 0; t < 512; ++t) {
    const int tn = (t < 511) ? t + 1 : 511;
    float xpre = 0.f;
    if (tid < 128) xpre = xb[((size_t)(b0 + m2)*512 + tn)*32 + c2];

    half8 A[5];
    #pragma unroll
    for (int kb = 0; kb < 5; ++kb)
      A[kb] = *(const half8*)&hx[l15][kb*32 + lq*8];

    f32x4 Cr[2], Cz[2], Cnh[2], Cni[2];
    #pragma unroll
    for (int sub = 0; sub < 2; ++sub) {
      Cr[sub] = (f32x4){0.f,0.f,0.f,0.f};
      Cz[sub] = (f32x4){0.f,0.f,0.f,0.f};
      Cnh[sub] = (f32x4){0.f,0.f,0.f,0.f};
      Cni[sub] = (f32x4){0.f,0.f,0.f,0.f};
    }
    #pragma unroll
    for (int sub = 0; sub < 2; ++sub) {
      #pragma unroll
      for (int kb = 0; kb < 5; ++kb) {
        Cr[sub] = __builtin_amdgcn_mfma_f32_16x16x32_f16(A[kb], Bf[sub][kb],     Cr[sub], 0, 0, 0);
        Cz[sub] = __builtin_amdgcn_mfma_f32_16x16x32_f16(A[kb], Bf[2 + sub][kb], Cz[sub], 0, 0, 0);
      }
      #pragma unroll
      for (int kb = 0; kb < 4; ++kb)
        Cnh[sub] = __builtin_amdgcn_mfma_f32_16x16x32_f16(A[kb], Bf[4 + sub][kb], Cnh[sub], 0, 0, 0);
      Cni[sub] = __builtin_amdgcn_mfma_f32_16x16x32_f16(A[4], Bf[4 + sub][4], Cni[sub], 0, 0, 0);
    }
    __syncthreads();   // all hx reads done

    #pragma unroll
    for (int sub = 0; sub < 2; ++sub)
      #pragma unroll
      for (int i = 0; i < 4; ++i) {
        float r = 1.f / (1.f + __expf(-(Cr[sub][i] + br[sub])));
        float z = 1.f / (1.f + __expf(-(Cz[sub][i] + bz[sub])));
        float narg = (Cni[sub][i] + bni[sub]) + r * (Cnh[sub][i] + bnh[sub]);
        float n = 1.f - 2.f / (__expf(2.f*narg) + 1.f);
        float hnew = (1.f - z)*n + z*hreg[sub][i];
        hreg[sub][i] = hnew;
        if (lq == 0)
          hx[i][wid*32 + sub*16 + l15] = (_Float16)hnew;
      }
    if (tid < 128) hx[m2][128 + c2] = (_Float16)xpre;
    __syncthreads();

    if (tid < 128) {
      half4 hv = *(const half4*)&hx[m2][c2*4];
      *(half4*)((void*)&enc_out[((size_t)(b0 + m2)*512 + t)*128 + c2*4]) = hv;
    }
  }

  if (lq == 0)
    #pragma unroll
    for (int sub = 0; sub < 2; ++sub)
      #pragma unroll
      for (int i = 0; i < 4; ++i)
        hfin[(size_t)(b0 + i)*128 + wid*32 + sub*16 + l15] = hreg[sub][i];
}

// ================= decoder: MFMA, weights in VGPRs, 8 waves, E in LDS =================
struct DecSmem {
  _Float16 E[512*128];    // 128 KB
  float lw[512];
  float wsm[512];
  float ctxp[16*128];     // overlaid after B6: garr[256] | nharr[128] | niarr[128]
  float hsm[128];
  _Float16 hy[160];       // [h | y] fp16 (logits A)
  _Float16 cxh[256];      // [ctx | h] fp16 (GRU A)
  float red[16];
  float outp[512];
  float absm[512];
  float bRZ[256];
  float bNH[128];
  float bNI[128];
  _Float16 o1[128*32];    // out1T staged
  float o1b[32];
  float o2w[32];
  float o2b;
};

__global__ void __launch_bounds__(512, 2) dec_kernel(const float* __restrict__ xb,
    const __half* __restrict__ enc_out, const float* __restrict__ hfin,
    const __half* __restrict__ attnF, const float* __restrict__ attn_b,
    const __half* __restrict__ decF,
    const float* __restrict__ dbih, const float* __restrict__ dbhh,
    const __half* __restrict__ out1T, const float* __restrict__ out1_b,
    const float* __restrict__ out2_W, const float* __restrict__ out2_b,
    float* __restrict__ out) {
  __shared__ __align__(16) DecSmem sm;
  const int tid = threadIdx.x, lane = tid & 63, wid = tid >> 6;
  const int l15 = lane & 15, lq = lane >> 4;
  const int b = blockIdx.x;

  // ---- persistent B-fragments in VGPRs (loaded once) ----
  const half8* aFp = (const half8*)attnF;
  const half8* dFp = (const half8*)decF;
  half8 Bl[4][5];
  #pragma unroll
  for (int stt = 0; stt < 4; ++stt)
    #pragma unroll
    for (int kb = 0; kb < 5; ++kb)
      Bl[stt][kb] = aFp[((wid*4 + stt)*5 + kb)*64 + lane];
  const int w4rz = wid & 3, g2 = wid >> 2;      // rz tiles {2w,2w+1}
  const int w4n = wid >> 1, subn = wid & 1;     // nh/ni tile {w}
  half8 Brz[2][8], Bnh[4], Bni[4];
  #pragma unroll
  for (int s = 0; s < 2; ++s)
    #pragma unroll
    for (int kb = 0; kb < 8; ++kb)
      Brz[s][kb] = dFp[(w4rz*48 + g2*16 + s*8 + kb)*64 + lane];
  #pragma unroll
  for (int kb = 0; kb < 4; ++kb) {
    Bnh[kb] = dFp[(w4n*48 + 32 + subn*4 + kb)*64 + lane];
    Bni[kb] = dFp[(w4n*48 + 40 + subn*4 + kb)*64 + lane];
  }

  // ---- staging ----
  { const half8* src = (const half8*)(enc_out + (size_t)b*512*128);
    half8* dst = (half8*)sm.E;
    for (int i = tid; i < 8192; i += 512) dst[i] = src[i]; }
  if (tid < 128) { float hv = hfin[(size_t)b*128 + tid];
    sm.hsm[tid] = hv; sm.hy[tid] = (_Float16)hv; sm.cxh[128 + tid] = (_Float16)hv; }
  if (tid < 32) sm.hy[128 + tid] = (_Float16)xb[((size_t)b*512 + 511)*32 + tid];
  sm.absm[tid] = attn_b[tid];
  if (tid < 256) sm.bRZ[tid] = dbih[tid] + dbhh[tid];
  if (tid < 128) { sm.bNH[tid] = dbhh[256 + tid]; sm.bNI[tid] = dbih[256 + tid]; }
  { const uint4* s4 = (const uint4*)out1T; uint4* d4 = (uint4*)sm.o1;
    if (tid < 512) d4[tid] = s4[tid]; }
  if (tid < 32) { sm.o1b[tid] = out1_b[tid]; sm.o2w[tid] = out2_W[tid]; }
  if (tid == 0) sm.o2b = out2_b[0];
  __syncthreads();

  const half8 Az = {};
  float* garr  = sm.ctxp;         // [0,256)  r|z row-0 outputs
  float* nharr = sm.ctxp + 256;   // [0,128)
  float* niarr = sm.ctxp + 384;   // [0,128)

  for (int tt = 0; tt < TO; ++tt) {
    // ---- logits: [1x160]@[160x512], wave w -> s-tiles {4w..4w+3} ----
    half8 A[5];
    #pragma unroll
    for (int kb = 0; kb < 5; ++kb)
      A[kb] = (l15 == 0) ? *(const half8*)&sm.hy[kb*32 + lq*8] : Az;
    f32x4 CL[4];
    #pragma unroll
    for (int stt = 0; stt < 4; ++stt) CL[stt] = (f32x4){0.f,0.f,0.f,0.f};
    #pragma unroll
    for (int stt = 0; stt < 4; ++stt)
      #pragma unroll
      for (int kb = 0; kb < 5; ++kb)
        CL[stt] = __builtin_amdgcn_mfma_f32_16x16x32_f16(A[kb], Bl[stt][kb], CL[stt], 0, 0, 0);
    if (lane < 16) {
      #pragma unroll
      for (int stt = 0; stt < 4; ++stt) {
        int s = (wid*4 + stt)*16 + lane;
        sm.lw[s] = CL[stt][0] + sm.absm[s];
      }
    }
    __syncthreads();  // B1

    // ---- softmax over 512 (1 logit/thread) ----
    float v = sm.lw[tid];
    float mx = v;
    #pragma unroll
    for (int off = 1; off < 64; off <<= 1) mx = fmaxf(mx, __shfl_xor(mx, off));
    if (lane == 0) sm.red[wid] = mx;
    __syncthreads();  // B2
    float M = sm.red[0];
    #pragma unroll
    for (int g = 1; g < 8; ++g) M = fmaxf(M, sm.red[g]);
    float e = __expf(v - M);
    float ss = e;
    #pragma unroll
    for (int off = 1; off < 64; off <<= 1) ss += __shfl_xor(ss, off);
    if (lane == 0) sm.red[8 + wid] = ss;
    __syncthreads();  // B3
    float tot = sm.red[8];
    #pragma unroll
    for (int g = 1; g < 8; ++g) tot += sm.red[8 + g];
    sm.wsm[tid] = e * (1.f / tot);
    __syncthreads();  // B4

    // ---- ctx = w @ E (16 s-groups x 32) ----
    { const int hq = tid & 31, sg = tid >> 5;
      float c0 = 0.f, c1 = 0.f, c2 = 0.f, c3 = 0.f;
      #pragma unroll 8
      for (int ii = 0; ii < 32; ++ii) {
        int s = sg*32 + ii;
        float wv = sm.wsm[s];
        half4 ev = *(const half4*)&sm.E[s*128 + hq*4];
        c0 += wv * (float)ev[0]; c1 += wv * (float)ev[1];
        c2 += wv * (float)ev[2]; c3 += wv * (float)ev[3];
      }
      f32x4 cc = {c0, c1, c2, c3};
      *(f32x4*)&sm.ctxp[sg*128 + hq*4] = cc; }
    __syncthreads();  // B5
    if (tid < 128) {
      float c = 0.f;
      #pragma unroll
      for (int g = 0; g < 16; ++g) c += sm.ctxp[g*128 + tid];
      sm.cxh[tid] = (_Float16)c;
    }
    __syncthreads();  // B6

    // ---- GRU MFMA: wave w -> rz tiles {2w,2w+1}, nh/ni tile {w} ----
    half8 Ag[8];
    #pragma unroll
    for (int kb = 0; kb < 8; ++kb)
      Ag[kb] = (l15 == 0) ? *(const half8*)&sm.cxh[kb*32 + lq*8] : Az;
    f32x4 Crz[2], Cnh, Cni;
    Crz[0] = (f32x4){0.f,0.f,0.f,0.f}; Crz[1] = (f32x4){0.f,0.f,0.f,0.f};
    Cnh = (f32x4){0.f,0.f,0.f,0.f};    Cni = (f32x4){0.f,0.f,0.f,0.f};
    #pragma unroll
    for (int s = 0; s < 2; ++s)
      #pragma unroll
      for (int kb = 0; kb < 8; ++kb)
        Crz[s] = __builtin_amdgcn_mfma_f32_16x16x32_f16(Ag[kb], Brz[s][kb], Crz[s], 0, 0, 0);
    #pragma unroll
    for (int kb = 0; kb < 4; ++kb) {
      Cnh = __builtin_amdgcn_mfma_f32_16x16x32_f16(Ag[4 + kb], Bnh[kb], Cnh, 0, 0, 0);
      Cni = __builtin_amdgcn_mfma_f32_16x16x32_f16(Ag[kb],     Bni[kb], Cni, 0, 0, 0);
    }
    if (lane < 16) {
      #pragma unroll
      for (int s = 0; s < 2; ++s)
        garr[(2*wid + s)*16 + lane] = Crz[s][0];
      nharr[wid*16 + lane] = Cnh[0];
      niarr[wid*16 + lane] = Cni[0];
    }
    __syncthreads();  // B7

    // ---- gates (tid<128 = one h-col each) ----
    if (tid < 128) {
      int j = tid;
      float r = 1.f / (1.f + __expf(-(garr[j] + sm.bRZ[j])));
      float z = 1.f / (1.f + __expf(-(garr[128 + j] + sm.bRZ[128 + j])));
      float narg = (niarr[j] + sm.bNI[j]) + r * (nharr[j] + sm.bNH[j]);
      float n = 1.f - 2.f / (__expf(2.f*narg) + 1.f);
      float hnew = (1.f - z)*n + z*sm.hsm[j];
      sm.hsm[j] = hnew;
      sm.hy[j] = (_Float16)hnew;
      sm.cxh[128 + j] = (_Float16)hnew;
    }
    __syncthreads();  // B8

    // ---- out1 (16 k-groups x 8) ----
    { int f = tid & 31, kq = tid >> 5;
      float a = 0.f;
      #pragma unroll
      for (int k2 = 0; k2 < 8; ++k2) { int k = kq*8 + k2; a += (float)sm.o1[k*32 + f] * sm.hsm[k]; }
      sm.outp[kq*32 + f] = a; }
    __syncthreads();  // B9
    if (tid < 32) {
      float o = sm.o1b[tid];
      #pragma unroll
      for (int g = 0; g < 16; ++g) o += sm.outp[g*32 + tid];
      sm.hy[128 + tid] = (_Float16)o;               // raw out feeds next attention
      float vv = fmaxf(o, 0.f) * sm.o2w[tid];
      #pragma unroll
      for (int off = 1; off < 32; off <<= 1) vv += __shfl_xor(vv, off);
      if (tid == 0) out[(size_t)b*TO + tt] = fmaxf(vv + sm.o2b, 0.f);
    }
    __syncthreads();  // B10
  }
}

extern "C" void kernel_launch(void* const* d_in, const int* in_sizes, int n_in,
                              void* d_out, int out_size, void* d_ws, size_t ws_size,
                              hipStream_t stream) {
  const float* xb      = (const float*)d_in[0];
  const float* enc_Wih = (const float*)d_in[1];
  const float* enc_Whh = (const float*)d_in[2];
  const float* enc_bih = (const float*)d_in[3];
  const float* enc_bhh = (const float*)d_in[4];
  const float* attn_W  = (const float*)d_in[5];
  const float* attn_b  = (const float*)d_in[6];
  const float* dec_Wih = (const float*)d_in[7];
  const float* dec_Whh = (const float*)d_in[8];
  const float* dec_bih = (const float*)d_in[9];
  const float* dec_bhh = (const float*)d_in[10];
  const float* out1_W  = (const float*)d_in[11];
  const float* out1_b  = (const float*)d_in[12];
  const float* out2_W  = (const float*)d_in[13];
  const float* out2_b  = (const float*)d_in[14];

  char* ws = (char*)d_ws;
  __half* enc_out = (__half*)(ws + OFF_ENCOUT);
  float*  hfin    = (float*)(ws + OFF_HFIN);
  __half* attnF   = (__half*)(ws + OFF_ATTNF);
  __half* decF    = (__half*)(ws + OFF_DECF);
  __half* out1T   = (__half*)(ws + OFF_OUT1T);
  __half* Wf      = (__half*)(ws + OFF_WF);

  prep_kernel<<<960, 256, 0, stream>>>(attn_W, dec_Wih, dec_Whh, out1_W, enc_Wih, enc_Whh,
                                       attnF, decF, out1T, Wf);
  enc_kernel<<<512, 256, 0, stream>>>(xb, Wf, enc_bih, enc_bhh, enc_out, hfin);
  dec_kernel<<<2048, 512, 0, stream>>>(xb, enc_out, hfin, attnF, attn_b, decF,
                                       dec_bih, dec_bhh, out1T, out1_b, out2_W, out2_b,
                                       (float*)d_out);
}

// Round 6
// 1302.145 us; speedup vs baseline: 1.6462x; 1.6462x over previous
//
#include <hip/hip_runtime.h>
#include <hip/hip_fp16.h>

#define BB 2048
#define SS 512
#define FF 32
#define HH 128
#define TO 24
#define LOG2E 1.4426950408889634f

typedef unsigned int uint;
using half4 = __attribute__((ext_vector_type(4))) _Float16;
using half8 = __attribute__((ext_vector_type(8))) _Float16;
using f32x4 = __attribute__((ext_vector_type(4))) float;

// ---- workspace layout (bytes) ----
#define OFF_ENCOUT 0ull                                      // half[B][S][H]
#define OFF_HFIN  (OFF_ENCOUT + (size_t)BB*SS*HH*2)          // float[B][H]
#define OFF_ATTNF (OFF_HFIN + (size_t)BB*HH*4)               // half[81920]  logits B-frags
#define OFF_DECF  (OFF_ATTNF + (size_t)81920*2)              // half[98304]  GRU B-frags
#define OFF_OUT1T (OFF_DECF + (size_t)98304*2)               // half[128*32]
#define OFF_WF    (OFF_OUT1T + (size_t)4096*2)               // half[61440]  enc B-frags

// ================= prep: pack weights into MFMA fragment order =================
__global__ void prep_kernel(const float* attn_W, const float* dec_Wih, const float* dec_Whh,
                            const float* out1_W, const float* enc_Wih, const float* enc_Whh,
                            __half* attnF, __half* decF, __half* out1T, __half* Wf) {
  int i = blockIdx.x * 256 + threadIdx.x;
  if (i < 81920) {
    int e = i & 7, l = (i >> 3) & 63, kb = (i >> 9) % 5, st = (i / 2560) & 7, w = i / 20480;
    int k = kb*32 + ((l >> 4) << 3) + e;
    int s = w*128 + st*16 + (l & 15);
    attnF[i] = __float2half(attn_W[s*160 + k]);
    return;
  }
  i -= 81920;
  if (i < 98304) {
    int e = i & 7, l = (i >> 3) & 63, fi = (i >> 9) % 48, w = i / 24576;
    int lq = l >> 4, l15 = l & 15;
    float val;
    if (fi < 32) {            // r/z combined [ctx|h] K=256
      int g2 = fi >> 4, sub = (fi >> 3) & 1, kb = fi & 7;
      int k = kb*32 + lq*8 + e, j = w*32 + sub*16 + l15, jg = g2*128 + j;
      val = (k < 128) ? dec_Wih[jg*128 + k] : dec_Whh[jg*128 + (k - 128)];
    } else {                  // nh (Whh) then ni (Wih), K=128 each
      int f2 = fi - 32, cat = f2 >> 3, sub = (f2 >> 2) & 1, kb4 = f2 & 3;
      int k = kb4*32 + lq*8 + e, j = 256 + w*32 + sub*16 + l15;
      val = cat ? dec_Wih[j*128 + k] : dec_Whh[j*128 + k];
    }
    decF[i] = __float2half(val);
    return;
  }
  i -= 98304;
  if (i < 4096) {
    int k = i >> 5, f = i & 31;
    out1T[i] = __float2half(out1_W[f*128 + k]);
    return;
  }
  i -= 4096;
  if (i < 61440) {
    int e = i & 7, l = (i >> 3) & 63, q = i >> 9;
    int kb = q % 5, tt = (q / 5) % 6, w = q / 30;
    int g = tt >> 1, sub = tt & 1;
    int k = kb*32 + ((l >> 4) << 3) + e;
    int J = g*128 + w*32 + sub*16 + (l & 15);
    float v = (k < 128) ? enc_Whh[J*128 + k] : enc_Wih[J*32 + (k - 128)];
    Wf[i] = __float2half(v);
  }
}

// ================= encoder: MFMA, 8 batches/block, 256 blocks =================
#define HXS 168

__global__ void __launch_bounds__(256, 1) enc_kernel(
    const float* __restrict__ xb, const __half* __restrict__ Wf,
    const float* __restrict__ bih, const float* __restrict__ bhh,
    __half* __restrict__ enc_out, float* __restrict__ hfin) {
  __shared__ __align__(16) _Float16 hx[16][HXS];   // rows 0..7 live, 8..15 zero
  const int tid  = threadIdx.x;
  const int lane = tid & 63, wid = tid >> 6;
  const int l15  = lane & 15, lq = lane >> 4;
  const int b0   = blockIdx.x * 8;

  half8 Bf[6][5];
  { const half8* wfp = (const half8*)Wf;
    #pragma unroll
    for (int tt = 0; tt < 6; ++tt)
      #pragma unroll
      for (int kb = 0; kb < 5; ++kb)
        Bf[tt][kb] = wfp[((wid*6 + tt)*5 + kb)*64 + lane];
  }

  float br[2], bz[2], bnh[2], bni[2];
  #pragma unroll
  for (int sub = 0; sub < 2; ++sub) {
    int j = wid*32 + sub*16 + l15;
    br[sub]  = bih[j]       + bhh[j];
    bz[sub]  = bih[128 + j] + bhh[128 + j];
    bnh[sub] = bhh[256 + j];
    bni[sub] = bih[256 + j];
  }
  float hreg[2][4] = {{0.f,0.f,0.f,0.f},{0.f,0.f,0.f,0.f}};

  const int m2 = tid >> 5, c2 = tid & 31;   // staging: 8 rows x 32 cols

  for (int i = tid; i < 16*HXS; i += 256) (&hx[0][0])[i] = (_Float16)0.f;
  __syncthreads();
  hx[m2][128 + c2] = (_Float16)xb[((size_t)(b0 + m2)*512 + 0)*32 + c2];
  __syncthreads();

  for (int t = 0; t < 512; ++t) {
    const int tn = (t < 511) ? t + 1 : 511;
    float xpre = xb[((size_t)(b0 + m2)*512 + tn)*32 + c2];

    half8 A[5];
    #pragma unroll
    for (int kb = 0; kb < 5; ++kb)
      A[kb] = *(const half8*)&hx[l15][kb*32 + lq*8];

    f32x4 Cr[2], Cz[2], Cnh[2], Cni[2];
    #pragma unroll
    for (int sub = 0; sub < 2; ++sub) {
      Cr[sub] = (f32x4){0.f,0.f,0.f,0.f};
      Cz[sub] = (f32x4){0.f,0.f,0.f,0.f};
      Cnh[sub] = (f32x4){0.f,0.f,0.f,0.f};
      Cni[sub] = (f32x4){0.f,0.f,0.f,0.f};
    }
    #pragma unroll
    for (int sub = 0; sub < 2; ++sub) {
      #pragma unroll
      for (int kb = 0; kb < 5; ++kb) {
        Cr[sub] = __builtin_amdgcn_mfma_f32_16x16x32_f16(A[kb], Bf[sub][kb],     Cr[sub], 0, 0, 0);
        Cz[sub] = __builtin_amdgcn_mfma_f32_16x16x32_f16(A[kb], Bf[2 + sub][kb], Cz[sub], 0, 0, 0);
      }
      #pragma unroll
      for (int kb = 0; kb < 4; ++kb)
        Cnh[sub] = __builtin_amdgcn_mfma_f32_16x16x32_f16(A[kb], Bf[4 + sub][kb], Cnh[sub], 0, 0, 0);
      Cni[sub] = __builtin_amdgcn_mfma_f32_16x16x32_f16(A[4], Bf[4 + sub][4], Cni[sub], 0, 0, 0);
    }
    __syncthreads();   // all hx reads done

    #pragma unroll
    for (int sub = 0; sub < 2; ++sub)
      #pragma unroll
      for (int i = 0; i < 4; ++i) {
        float xr = Cr[sub][i] + br[sub];
        float xz = Cz[sub][i] + bz[sub];
        float r = __builtin_amdgcn_rcpf(1.f + __builtin_amdgcn_exp2f(-LOG2E*xr));
        float z = __builtin_amdgcn_rcpf(1.f + __builtin_amdgcn_exp2f(-LOG2E*xz));
        float narg = (Cni[sub][i] + bni[sub]) + r * (Cnh[sub][i] + bnh[sub]);
        float n = 1.f - 2.f*__builtin_amdgcn_rcpf(__builtin_amdgcn_exp2f((2.f*LOG2E)*narg) + 1.f);
        float hnew = n + z*(hreg[sub][i] - n);
        hreg[sub][i] = hnew;
        if (lq < 2)
          hx[4*lq + i][wid*32 + sub*16 + l15] = (_Float16)hnew;
      }
    hx[m2][128 + c2] = (_Float16)xpre;
    __syncthreads();

    { half4 hv = *(const half4*)&hx[m2][c2*4];
      *(half4*)((void*)&enc_out[((size_t)(b0 + m2)*512 + t)*128 + c2*4]) = hv; }
  }

  if (lq < 2)
    #pragma unroll
    for (int sub = 0; sub < 2; ++sub)
      #pragma unroll
      for (int i = 0; i < 4; ++i)
        hfin[(size_t)(b0 + 4*lq + i)*128 + wid*32 + sub*16 + l15] = hreg[sub][i];
}

// ================= decoder: MFMA, weights in VGPRs, 8 waves, E in LDS =================
struct DecSmem {
  _Float16 E[512*128];    // 128 KB
  float lw[512];
  float wsm[512];
  float ctxp[16*128];     // overlaid after B-cxh: garr[256] | nharr[128] | niarr[128]
  float hsm[128];
  _Float16 hy[160];       // [h | y] fp16 (logits A)
  _Float16 cxh[256];      // [ctx | h] fp16 (GRU A)
  float red[16];
  float outp[512];
  float absm[512];
  float bRZ[256];
  float bNH[128];
  float bNI[128];
  _Float16 o1[128*32];    // out1T staged
  float o1b[32];
  float o2w[32];
  float o2b;
};

__global__ void __launch_bounds__(512, 2) dec_kernel(const float* __restrict__ xb,
    const __half* __restrict__ enc_out, const float* __restrict__ hfin,
    const __half* __restrict__ attnF, const float* __restrict__ attn_b,
    const __half* __restrict__ decF,
    const float* __restrict__ dbih, const float* __restrict__ dbhh,
    const __half* __restrict__ out1T, const float* __restrict__ out1_b,
    const float* __restrict__ out2_W, const float* __restrict__ out2_b,
    float* __restrict__ out) {
  __shared__ __align__(16) DecSmem sm;
  const int tid = threadIdx.x, lane = tid & 63, wid = tid >> 6;
  const int l15 = lane & 15, lq = lane >> 4;
  const int b = blockIdx.x;

  // ---- persistent B-fragments in VGPRs (loaded once) ----
  const half8* aFp = (const half8*)attnF;
  const half8* dFp = (const half8*)decF;
  half8 Bl[4][5];
  #pragma unroll
  for (int stt = 0; stt < 4; ++stt)
    #pragma unroll
    for (int kb = 0; kb < 5; ++kb)
      Bl[stt][kb] = aFp[((wid*4 + stt)*5 + kb)*64 + lane];
  const int w4rz = wid & 3, g2 = wid >> 2;      // rz tiles
  const int w4n = wid >> 1, subn = wid & 1;     // nh/ni tiles
  half8 Brz[2][8], Bnh[4], Bni[4];
  #pragma unroll
  for (int s = 0; s < 2; ++s)
    #pragma unroll
    for (int kb = 0; kb < 8; ++kb)
      Brz[s][kb] = dFp[(w4rz*48 + g2*16 + s*8 + kb)*64 + lane];
  #pragma unroll
  for (int kb = 0; kb < 4; ++kb) {
    Bnh[kb] = dFp[(w4n*48 + 32 + subn*4 + kb)*64 + lane];
    Bni[kb] = dFp[(w4n*48 + 40 + subn*4 + kb)*64 + lane];
  }

  // ---- staging ----
  { const half8* src = (const half8*)(enc_out + (size_t)b*512*128);
    half8* dst = (half8*)sm.E;
    for (int i = tid; i < 8192; i += 512) dst[i] = src[i]; }
  if (tid < 128) { float hv = hfin[(size_t)b*128 + tid];
    sm.hsm[tid] = hv; sm.hy[tid] = (_Float16)hv; sm.cxh[128 + tid] = (_Float16)hv; }
  if (tid < 32) sm.hy[128 + tid] = (_Float16)xb[((size_t)b*512 + 511)*32 + tid];
  sm.absm[tid] = attn_b[tid];
  if (tid < 256) sm.bRZ[tid] = dbih[tid] + dbhh[tid];
  if (tid < 128) { sm.bNH[tid] = dbhh[256 + tid]; sm.bNI[tid] = dbih[256 + tid]; }
  { const uint4* s4 = (const uint4*)out1T; uint4* d4 = (uint4*)sm.o1;
    if (tid < 512) d4[tid] = s4[tid]; }
  if (tid < 32) { sm.o1b[tid] = out1_b[tid]; sm.o2w[tid] = out2_W[tid]; }
  if (tid == 0) sm.o2b = out2_b[0];
  __syncthreads();

  const half8 Az = {};
  float* garr  = sm.ctxp;         // [0,256)  r|z row-0 outputs
  float* nharr = sm.ctxp + 256;   // [0,128)
  float* niarr = sm.ctxp + 384;   // [0,128)

  for (int tt = 0; tt < TO; ++tt) {
    // ---- logits: [1x160]@[160x512], wave w -> s-tiles {4w..4w+3} ----
    half8 A[5];
    #pragma unroll
    for (int kb = 0; kb < 5; ++kb)
      A[kb] = (l15 == 0) ? *(const half8*)&sm.hy[kb*32 + lq*8] : Az;
    f32x4 CL[4];
    #pragma unroll
    for (int stt = 0; stt < 4; ++stt) CL[stt] = (f32x4){0.f,0.f,0.f,0.f};
    #pragma unroll
    for (int stt = 0; stt < 4; ++stt)
      #pragma unroll
      for (int kb = 0; kb < 5; ++kb)
        CL[stt] = __builtin_amdgcn_mfma_f32_16x16x32_f16(A[kb], Bl[stt][kb], CL[stt], 0, 0, 0);

    // ---- per-wave partial softmax (wave's 64 logits live in lanes 0-15) ----
    float vst[4];
    float mw = -1e30f, sw = 0.f;
    if (lane < 16) {
      #pragma unroll
      for (int stt = 0; stt < 4; ++stt) {
        int s = (wid*4 + stt)*16 + lane;
        vst[stt] = CL[stt][0] + sm.absm[s];
        sm.lw[s] = vst[stt];
      }
      mw = fmaxf(fmaxf(vst[0], vst[1]), fmaxf(vst[2], vst[3]));
    }
    #pragma unroll
    for (int off = 1; off < 16; off <<= 1) mw = fmaxf(mw, __shfl_xor(mw, off, 16));
    if (lane < 16) {
      #pragma unroll
      for (int stt = 0; stt < 4; ++stt) sw += __builtin_amdgcn_exp2f(LOG2E*(vst[stt] - mw));
    }
    #pragma unroll
    for (int off = 1; off < 16; off <<= 1) sw += __shfl_xor(sw, off, 16);
    if (lane == 0) { sm.red[wid] = mw; sm.red[8 + wid] = sw; }
    __syncthreads();  // B1

    float M = sm.red[0];
    #pragma unroll
    for (int g = 1; g < 8; ++g) M = fmaxf(M, sm.red[g]);
    float tot = 0.f;
    #pragma unroll
    for (int g = 0; g < 8; ++g) tot += sm.red[8 + g] * __builtin_amdgcn_exp2f(LOG2E*(sm.red[g] - M));
    sm.wsm[tid] = __builtin_amdgcn_exp2f(LOG2E*(sm.lw[tid] - M)) * __builtin_amdgcn_rcpf(tot);
    __syncthreads();  // B2

    // ---- ctx = w @ E (16 s-groups x 32) ----
    { const int hq = tid & 31, sg = tid >> 5;
      float c0 = 0.f, c1 = 0.f, c2 = 0.f, c3 = 0.f;
      #pragma unroll 8
      for (int ii = 0; ii < 32; ++ii) {
        int s = sg*32 + ii;
        float wv = sm.wsm[s];
        half4 ev = *(const half4*)&sm.E[s*128 + hq*4];
        c0 += wv * (float)ev[0]; c1 += wv * (float)ev[1];
        c2 += wv * (float)ev[2]; c3 += wv * (float)ev[3];
      }
      f32x4 cc = {c0, c1, c2, c3};
      *(f32x4*)&sm.ctxp[sg*128 + hq*4] = cc; }
    __syncthreads();  // B3
    if (tid < 128) {
      float c = 0.f;
      #pragma unroll
      for (int g = 0; g < 16; ++g) c += sm.ctxp[g*128 + tid];
      sm.cxh[tid] = (_Float16)c;
    }
    __syncthreads();  // B4

    // ---- GRU MFMA ----
    half8 Ag[8];
    #pragma unroll
    for (int kb = 0; kb < 8; ++kb)
      Ag[kb] = (l15 == 0) ? *(const half8*)&sm.cxh[kb*32 + lq*8] : Az;
    f32x4 Crz[2], Cnh, Cni;
    Crz[0] = (f32x4){0.f,0.f,0.f,0.f}; Crz[1] = (f32x4){0.f,0.f,0.f,0.f};
    Cnh = (f32x4){0.f,0.f,0.f,0.f};    Cni = (f32x4){0.f,0.f,0.f,0.f};
    #pragma unroll
    for (int s = 0; s < 2; ++s)
      #pragma unroll
      for (int kb = 0; kb < 8; ++kb)
        Crz[s] = __builtin_amdgcn_mfma_f32_16x16x32_f16(Ag[kb], Brz[s][kb], Crz[s], 0, 0, 0);
    #pragma unroll
    for (int kb = 0; kb < 4; ++kb) {
      Cnh = __builtin_amdgcn_mfma_f32_16x16x32_f16(Ag[4 + kb], Bnh[kb], Cnh, 0, 0, 0);
      Cni = __builtin_amdgcn_mfma_f32_16x16x32_f16(Ag[kb],     Bni[kb], Cni, 0, 0, 0);
    }
    if (lane < 16) {
      #pragma unroll
      for (int s = 0; s < 2; ++s)
        garr[(2*wid + s)*16 + lane] = Crz[s][0];
      nharr[wid*16 + lane] = Cnh[0];
      niarr[wid*16 + lane] = Cni[0];
    }
    __syncthreads();  // B5

    // ---- gates (tid<128 = one h-col each) ----
    if (tid < 128) {
      int j = tid;
      float xr = garr[j] + sm.bRZ[j];
      float xz = garr[128 + j] + sm.bRZ[128 + j];
      float r = __builtin_amdgcn_rcpf(1.f + __builtin_amdgcn_exp2f(-LOG2E*xr));
      float z = __builtin_amdgcn_rcpf(1.f + __builtin_amdgcn_exp2f(-LOG2E*xz));
      float narg = (niarr[j] + sm.bNI[j]) + r * (nharr[j] + sm.bNH[j]);
      float n = 1.f - 2.f*__builtin_amdgcn_rcpf(__builtin_amdgcn_exp2f((2.f*LOG2E)*narg) + 1.f);
      float hnew = n + z*(sm.hsm[j] - n);
      sm.hsm[j] = hnew;
      sm.hy[j] = (_Float16)hnew;
      sm.cxh[128 + j] = (_Float16)hnew;
    }
    __syncthreads();  // B6

    // ---- out1 (16 k-groups x 8) ----
    { int f = tid & 31, kq = tid >> 5;
      float a = 0.f;
      #pragma unroll
      for (int k2 = 0; k2 < 8; ++k2) { int k = kq*8 + k2; a += (float)sm.o1[k*32 + f] * sm.hsm[k]; }
      sm.outp[kq*32 + f] = a; }
    __syncthreads();  // B7
    if (tid < 32) {
      float o = sm.o1b[tid];
      #pragma unroll
      for (int g = 0; g < 16; ++g) o += sm.outp[g*32 + tid];
      sm.hy[128 + tid] = (_Float16)o;               // raw out feeds next attention
      float vv = fmaxf(o, 0.f) * sm.o2w[tid];
      #pragma unroll
      for (int off = 1; off < 32; off <<= 1) vv += __shfl_xor(vv, off);
      if (tid == 0) out[(size_t)b*TO + tt] = fmaxf(vv + sm.o2b, 0.f);
    }
    __syncthreads();  // B8
  }
}

extern "C" void kernel_launch(void* const* d_in, const int* in_sizes, int n_in,
                              void* d_out, int out_size, void* d_ws, size_t ws_size,
                              hipStream_t stream) {
  const float* xb      = (const float*)d_in[0];
  const float* enc_Wih = (const float*)d_in[1];
  const float* enc_Whh = (const float*)d_in[2];
  const float* enc_bih = (const float*)d_in[3];
  const float* enc_bhh = (const float*)d_in[4];
  const float* attn_W  = (const float*)d_in[5];
  const float* attn_b  = (const float*)d_in[6];
  const float* dec_Wih = (const float*)d_in[7];
  const float* dec_Whh = (const float*)d_in[8];
  const float* dec_bih = (const float*)d_in[9];
  const float* dec_bhh = (const float*)d_in[10];
  const float* out1_W  = (const float*)d_in[11];
  const float* out1_b  = (const float*)d_in[12];
  const float* out2_W  = (const float*)d_in[13];
  const float* out2_b  = (const float*)d_in[14];

  char* ws = (char*)d_ws;
  __half* enc_out = (__half*)(ws + OFF_ENCOUT);
  float*  hfin    = (float*)(ws + OFF_HFIN);
  __half* attnF   = (__half*)(ws + OFF_ATTNF);
  __half* decF    = (__half*)(ws + OFF_DECF);
  __half* out1T   = (__half*)(ws + OFF_OUT1T);
  __half* Wf      = (__half*)(ws + OFF_WF);

  prep_kernel<<<960, 256, 0, stream>>>(attn_W, dec_Wih, dec_Whh, out1_W, enc_Wih, enc_Whh,
                                       attnF, decF, out1T, Wf);
  enc_kernel<<<256, 256, 0, stream>>>(xb, Wf, enc_bih, enc_bhh, enc_out, hfin);
  dec_kernel<<<2048, 512, 0, stream>>>(xb, enc_out, hfin, attnF, attn_b, decF,
                                       dec_bih, dec_bhh, out1T, out1_b, out2_W, out2_b,
                                       (float*)d_out);
}